// Round 17
// baseline (114.775 us; speedup 1.0000x reference)
//
#include <hip/hip_runtime.h>
#include <cstddef>
#include <cstdint>

namespace {

typedef _Float16 half8 __attribute__((ext_vector_type(8)));
typedef _Float16 half4 __attribute__((ext_vector_type(4)));
typedef _Float16 half2v __attribute__((ext_vector_type(2)));
typedef float f32x4 __attribute__((ext_vector_type(4)));

constexpr int Bn   = 4;
constexpr int Ln   = 1024;
constexpr int INn  = 256;
constexpr int DMn  = 1024;
constexpr int DSn  = 16;
constexpr int DCn  = 4;
constexpr int DIn  = 2048;
constexpr int DTRn = 64;
constexpr int XPW  = DTRn + DSn;    // 80
constexpr int NCHUNK = 32;
constexpr int CHUNK  = Ln / NCHUNK; // 32
constexpr int WCH  = 32;
constexpr int ML   = Bn * Ln;       // 4096

__device__ __forceinline__ float silu_(float x) { return x / (1.f + __expf(-x)); }
__device__ __forceinline__ float softplus_(float x) {
    return fmaxf(x, 0.f) + __logf(1.f + __expf(-fabsf(x)));
}

// ================= prep (block-range dispatch) =================
// [0,2048)      : in_proj u-half f2h + badd
// [2048,3072)   : x f2h ; [3072,3200): dt_w f2h
// [3200,3456)   : W_emb -> W_embT fp16
// [3456,3712)   : x_proj pad-cvt
// [3712,3968)   : weff partials
// 3968          : out init
// [3969,4225)   : e_last[b][m] = x[b,L-1,:] . W_emb[m,:]
__global__ __launch_bounds__(256)
void prep_mega(const float* __restrict__ x, _Float16* __restrict__ xh,
               const float* __restrict__ ip, _Float16* __restrict__ iph,
               const float* __restrict__ dtw, _Float16* __restrict__ dtwh,
               const float* __restrict__ W_emb, _Float16* __restrict__ W_embT,
               const float* __restrict__ x_proj, _Float16* __restrict__ xp_h,
               const float* __restrict__ fc_w, const float* __restrict__ out_w,
               float* __restrict__ wp,
               const float* __restrict__ b_emb, float* __restrict__ badd,
               const float* __restrict__ fc_b, float* __restrict__ out,
               float* __restrict__ e_last) {
    __shared__ float tile[32][33];
    const int bid = blockIdx.x, tid = threadIdx.x;
    if (bid < 2048) {
        const int n = bid;
        const float4 v = ((const float4*)ip)[n * 256 + tid];
        ((half4*)iph)[n * 256 + tid] =
            half4{(_Float16)v.x, (_Float16)v.y, (_Float16)v.z, (_Float16)v.w};
        const float4 bv = ((const float4*)b_emb)[tid];
        float s = v.x * bv.x + v.y * bv.y + v.z * bv.z + v.w * bv.w;
        for (int off = 32; off > 0; off >>= 1) s += __shfl_down(s, off);
        if ((tid & 63) == 0) tile[0][tid >> 6] = s;
        __syncthreads();
        if (tid == 0) badd[n] = tile[0][0] + tile[0][1] + tile[0][2] + tile[0][3];
    } else if (bid < 3200) {
        const float* in; _Float16* outp; int i;
        if (bid < 3072) { in = x;   outp = xh;   i = (bid - 2048) * 256 + tid; }
        else            { in = dtw; outp = dtwh; i = (bid - 3072) * 256 + tid; }
        const float4 v = ((const float4*)in)[i];
        ((half4*)outp)[i] = half4{(_Float16)v.x, (_Float16)v.y, (_Float16)v.z, (_Float16)v.w};
    } else if (bid < 3456) {
        const int bx = bid - 3200;
        const int m0 = (bx & 31) * 32, c0 = (bx >> 5) * 32;
        const int lc = tid & 31, lr = tid >> 5;
        #pragma unroll
        for (int ph = 0; ph < 4; ++ph)
            tile[lr + ph * 8][lc] = W_emb[(size_t)(m0 + lr + ph * 8) * INn + c0 + lc];
        __syncthreads();
        #pragma unroll
        for (int ph = 0; ph < 4; ++ph)
            W_embT[(size_t)(c0 + lr + ph * 8) * DMn + m0 + lc] = (_Float16)tile[lc][lr + ph * 8];
    } else if (bid < 3712) {
        const int i = (bid - 3456) * 256 + tid;
        const int r = i >> 9;
        const int c4 = i & 511;
        half4 h;
        if (r < XPW) {
            const float4 v = ((const float4*)(x_proj + (size_t)r * DIn))[c4];
            h = half4{(_Float16)v.x, (_Float16)v.y, (_Float16)v.z, (_Float16)v.w};
        } else {
            h = half4{(_Float16)0.f, (_Float16)0.f, (_Float16)0.f, (_Float16)0.f};
        }
        ((half4*)(xp_h + (size_t)r * DIn))[c4] = h;
    } else if (bid < 3968) {
        const int bx = bid - 3712;
        const int d = (bx & 7) * 256 + tid;
        const int c = bx >> 3;
        const int mstep = DMn / WCH;
        float s = 0.f;
        for (int m = c * mstep; m < (c + 1) * mstep; ++m)
            s += fc_w[m] * out_w[(size_t)m * DIn + d];
        wp[(size_t)c * DIn + d] = s;
    } else if (bid == 3968) {
        if (tid < Bn) out[tid] = fc_b[0];
    } else {
        const int m = (bid - 3969) * 4 + (tid >> 6);   // 0..1023
        const int lane = tid & 63;
        const float4 wq = ((const float4*)(W_emb + (size_t)m * INn))[lane];
        float s0, s1, s2, s3;
        {
            const float4 v = ((const float4*)(x + ((size_t)0 * Ln + (Ln - 1)) * INn))[lane];
            s0 = wq.x * v.x + wq.y * v.y + wq.z * v.z + wq.w * v.w;
        }
        {
            const float4 v = ((const float4*)(x + ((size_t)1 * Ln + (Ln - 1)) * INn))[lane];
            s1 = wq.x * v.x + wq.y * v.y + wq.z * v.z + wq.w * v.w;
        }
        {
            const float4 v = ((const float4*)(x + ((size_t)2 * Ln + (Ln - 1)) * INn))[lane];
            s2 = wq.x * v.x + wq.y * v.y + wq.z * v.z + wq.w * v.w;
        }
        {
            const float4 v = ((const float4*)(x + ((size_t)3 * Ln + (Ln - 1)) * INn))[lane];
            s3 = wq.x * v.x + wq.y * v.y + wq.z * v.z + wq.w * v.w;
        }
        for (int off = 32; off > 0; off >>= 1) {
            s0 += __shfl_down(s0, off);
            s1 += __shfl_down(s1, off);
            s2 += __shfl_down(s2, off);
            s3 += __shfl_down(s3, off);
        }
        if (lane == 0) {
            e_last[0 * DMn + m] = s0;
            e_last[1 * DMn + m] = s1;
            e_last[2 * DMn + m] = s2;
            e_last[3 * DMn + m] = s3;
        }
    }
}

// ---------------- generic split-K MFMA GEMM -> fp32 partials (proven) ----------------
__global__ __launch_bounds__(256)
void skgemm2(const _Float16* __restrict__ A, int lda,
             const _Float16* __restrict__ Bw, int ldb,
             float* __restrict__ P, int N, int Kc) {
    __shared__ _Float16 As[128 * 32];
    __shared__ _Float16 Bs[128 * 32];
    const int tid  = threadIdx.x;
    const int lane = tid & 63, wid = tid >> 6;
    const int wm = wid >> 1, wn = wid & 1;
    const int sk = blockIdx.x;
    const int m0 = blockIdx.y * 128;
    const int n0 = blockIdx.z * 128;
    const int M  = gridDim.y * 128;

    f32x4 acc[4][4] = {};
    const int kbeg = sk * Kc;
    for (int k0 = kbeg; k0 < kbeg + Kc; k0 += 32) {
        #pragma unroll
        for (int i = 0; i < 2; ++i) {
            const int off = tid * 16 + i * 4096;
            const int row = off >> 6;
            const int ch  = (off & 63) >> 1;
            __builtin_amdgcn_global_load_lds(
                (const __attribute__((address_space(1))) void*)(A + (size_t)(m0 + row) * lda + k0 + ch),
                (__attribute__((address_space(3))) void*)(&As[off >> 1]), 16, 0, 0);
            __builtin_amdgcn_global_load_lds(
                (const __attribute__((address_space(1))) void*)(Bw + (size_t)(n0 + row) * ldb + k0 + ch),
                (__attribute__((address_space(3))) void*)(&Bs[off >> 1]), 16, 0, 0);
        }
        __syncthreads();
        const int ar = lane & 15;
        const int kq = (lane >> 4) * 8;
        half8 af[4], bf[4];
        #pragma unroll
        for (int i = 0; i < 4; ++i)
            af[i] = *(const half8*)&As[(wm * 64 + i * 16 + ar) * 32 + kq];
        #pragma unroll
        for (int j = 0; j < 4; ++j)
            bf[j] = *(const half8*)&Bs[(wn * 64 + j * 16 + ar) * 32 + kq];
        #pragma unroll
        for (int i = 0; i < 4; ++i)
            #pragma unroll
            for (int j = 0; j < 4; ++j)
                acc[i][j] = __builtin_amdgcn_mfma_f32_16x16x32_f16(af[i], bf[j], acc[i][j], 0, 0, 0);
        __syncthreads();
    }
    const int cr = (lane >> 4) * 4;
    const int cn = lane & 15;
    #pragma unroll
    for (int i = 0; i < 4; ++i)
        #pragma unroll
        for (int j = 0; j < 4; ++j) {
            const int n = n0 + wn * 64 + j * 16 + cn;
            if (n < N) {
                #pragma unroll
                for (int r = 0; r < 4; ++r) {
                    const int m = m0 + wm * 64 + i * 16 + cr + r;
                    P[((size_t)sk * M + m) * N + n] = acc[i][j][r];
                }
            }
        }
}

// sum split-K partials -> fp16 (Wfold u-half)
__global__ __launch_bounds__(256)
void skcomb(const float* __restrict__ P, _Float16* __restrict__ out, int total, int nsk) {
    const int i = blockIdx.x * 256 + threadIdx.x;
    if (i >= total) return;
    float s = 0.f;
    for (int k = 0; k < nsk; ++k) s += P[(size_t)k * total + i];
    out[i] = (_Float16)s;
}

// node 6: dtB sum float4 ([0,320)) + clast ([320,336)) + zlast+badd ([336,848))
__global__ __launch_bounds__(256)
void skcombB_clast_zlast(const float* __restrict__ P, _Float16* __restrict__ dtBh,
                         const _Float16* __restrict__ u, const float* __restrict__ x_proj,
                         float* __restrict__ Clast,
                         const float* __restrict__ ip, const float* __restrict__ e_last,
                         const float* __restrict__ b_emb, float* __restrict__ zlast) {
    const int bid = blockIdx.x, tid = threadIdx.x;
    if (bid < 320) {
        const int i = bid * 256 + tid;          // float4 units over ML*XPW/4 = 81920
        const float4* P4 = (const float4*)P;
        float4 s = P4[i];
        #pragma unroll
        for (int k = 1; k < 8; ++k) {
            const float4 v = P4[(size_t)k * (ML * XPW / 4) + i];
            s.x += v.x; s.y += v.y; s.z += v.z; s.w += v.w;
        }
        ((half4*)dtBh)[i] = half4{(_Float16)s.x, (_Float16)s.y, (_Float16)s.z, (_Float16)s.w};
    } else if (bid < 336) {
        const int wave = tid >> 6, lane = tid & 63;
        const int task = (bid - 320) * 4 + wave;
        const int s_idx = task & 15, b = task >> 4;
        const _Float16* ur = u + ((size_t)b * Ln + (Ln - 1)) * DIn;
        const float* w = x_proj + (size_t)(XPW + s_idx) * DIn;
        float s = 0.f;
        for (int k = lane; k < DIn; k += 64) s += (float)ur[k] * w[k];
        for (int off = 32; off > 0; off >>= 1) s += __shfl_down(s, off);
        if (lane == 0) Clast[b * DSn + s_idx] = s;
    } else {
        // zlast[b][j] = e_last[b].in_proj_z[j] + in_proj_z[j].b_emb ; wave per j, 4 b's
        const int wave = tid >> 6, lane = tid & 63;
        const int j = (bid - 336) * 4 + wave;    // 0..2047
        const float4* row = (const float4*)(ip + (size_t)(DIn + j) * DMn);
        const float4 w0 = row[lane * 4 + 0];
        const float4 w1 = row[lane * 4 + 1];
        const float4 w2 = row[lane * 4 + 2];
        const float4 w3 = row[lane * 4 + 3];
        const float4* be = (const float4*)b_emb;
        const float4 e0b = be[lane * 4 + 0];
        const float4 e1b = be[lane * 4 + 1];
        const float4 e2b = be[lane * 4 + 2];
        const float4 e3b = be[lane * 4 + 3];
        float sb = w0.x * e0b.x + w0.y * e0b.y + w0.z * e0b.z + w0.w * e0b.w
                 + w1.x * e1b.x + w1.y * e1b.y + w1.z * e1b.z + w1.w * e1b.w
                 + w2.x * e2b.x + w2.y * e2b.y + w2.z * e2b.z + w2.w * e2b.w
                 + w3.x * e3b.x + w3.y * e3b.y + w3.z * e3b.z + w3.w * e3b.w;
        const float* el = e_last + lane * 16;
        float s0 = 0.f, s1 = 0.f, s2 = 0.f, s3 = 0.f;
        #pragma unroll
        for (int bb = 0; bb < 4; ++bb) {
            const float4 e0 = ((const float4*)(el + bb * DMn))[0];
            const float4 e1 = ((const float4*)(el + bb * DMn))[1];
            const float4 e2 = ((const float4*)(el + bb * DMn))[2];
            const float4 e3 = ((const float4*)(el + bb * DMn))[3];
            const float v = w0.x * e0.x + w0.y * e0.y + w0.z * e0.z + w0.w * e0.w
                          + w1.x * e1.x + w1.y * e1.y + w1.z * e1.z + w1.w * e1.w
                          + w2.x * e2.x + w2.y * e2.y + w2.z * e2.z + w2.w * e2.w
                          + w3.x * e3.x + w3.y * e3.y + w3.z * e3.z + w3.w * e3.w;
            if (bb == 0) s0 = v; else if (bb == 1) s1 = v; else if (bb == 2) s2 = v; else s3 = v;
        }
        for (int off = 32; off > 0; off >>= 1) {
            s0 += __shfl_down(s0, off);
            s1 += __shfl_down(s1, off);
            s2 += __shfl_down(s2, off);
            s3 += __shfl_down(s3, off);
            sb += __shfl_down(sb, off);
        }
        if (lane == 0) {
            zlast[0 * DIn + j] = s0 + sb;
            zlast[1 * DIn + j] = s1 + sb;
            zlast[2 * DIn + j] = s2 + sb;
            zlast[3 * DIn + j] = s3 + sb;
        }
    }
}

// ======== upre_conv: upre GEMM (+16-row halo) -> LDS -> conv+silu -> uh (proven R13) ========
__global__ __launch_bounds__(256)
void upre_conv(const _Float16* __restrict__ xh, const _Float16* __restrict__ Wfoldh,
               const float* __restrict__ badd,
               const float* __restrict__ cw, const float* __restrict__ cb,
               _Float16* __restrict__ uh) {
    __shared__ _Float16 smem[144 * 132];
    _Float16* As = smem;
    _Float16* Bs = smem + 144 * 32;
    _Float16 (*Ds)[132] = (_Float16 (*)[132])smem;

    const int tid = threadIdx.x;
    const int lane = tid & 63, wid = tid >> 6;
    const int wm = wid >> 1, wn = wid & 1;
    const int m0 = blockIdx.y * 128, n0 = blockIdx.x * 128;

    f32x4 acc[4][4] = {};
    f32x4 acch[4] = {};
    for (int k0 = 0; k0 < INn; k0 += 32) {
        #pragma unroll
        for (int i = 0; i < 2; ++i) {
            const int off = tid * 16 + i * 4096;
            const int row = off >> 6;
            const int ch  = (off & 63) >> 1;
            int srow = m0 - 16 + row;
            if (srow < 0) srow = 0;
            __builtin_amdgcn_global_load_lds(
                (const __attribute__((address_space(1))) void*)(xh + (size_t)srow * INn + k0 + ch),
                (__attribute__((address_space(3))) void*)(&As[off >> 1]), 16, 0, 0);
            const _Float16* gb = Wfoldh + (size_t)(n0 + row) * INn + k0 + ch;
            __builtin_amdgcn_global_load_lds(
                (const __attribute__((address_space(1))) void*)gb,
                (__attribute__((address_space(3))) void*)(&Bs[off >> 1]), 16, 0, 0);
        }
        if (tid < 64) {
            const int off = tid * 16 + 8192;
            const int row = off >> 6;
            const int ch  = (off & 63) >> 1;
            __builtin_amdgcn_global_load_lds(
                (const __attribute__((address_space(1))) void*)(xh + (size_t)(m0 - 16 + row) * INn + k0 + ch),
                (__attribute__((address_space(3))) void*)(&As[off >> 1]), 16, 0, 0);
        }
        __syncthreads();
        const int ar = lane & 15;
        const int kq = (lane >> 4) * 8;
        half8 af[4], bf[4];
        #pragma unroll
        for (int i = 0; i < 4; ++i)
            af[i] = *(const half8*)&As[(16 + wm * 64 + i * 16 + ar) * 32 + kq];
        #pragma unroll
        for (int j = 0; j < 4; ++j)
            bf[j] = *(const half8*)&Bs[(wn * 64 + j * 16 + ar) * 32 + kq];
        #pragma unroll
        for (int i = 0; i < 4; ++i)
            #pragma unroll
            for (int j = 0; j < 4; ++j)
                acc[i][j] = __builtin_amdgcn_mfma_f32_16x16x32_f16(af[i], bf[j], acc[i][j], 0, 0, 0);
        if (wm == 0) {
            const half8 afh = *(const half8*)&As[ar * 32 + kq];
            #pragma unroll
            for (int j = 0; j < 4; ++j)
                acch[j] = __builtin_amdgcn_mfma_f32_16x16x32_f16(afh, bf[j], acch[j], 0, 0, 0);
        }
        __syncthreads();
    }

    {
        const int cr = (lane >> 4) * 4;
        const int cn = lane & 15;
        #pragma unroll
        for (int i = 0; i < 4; ++i)
            #pragma unroll
            for (int j = 0; j < 4; ++j) {
                const int col = wn * 64 + j * 16 + cn;
                const float bb = badd[n0 + col];
                #pragma unroll
                for (int r = 0; r < 4; ++r)
                    Ds[16 + wm * 64 + i * 16 + cr + r][col] = (_Float16)(acc[i][j][r] + bb);
            }
        if (wm == 0) {
            #pragma unroll
            for (int j = 0; j < 4; ++j) {
                const int col = wn * 64 + j * 16 + cn;
                const float bb = badd[n0 + col];
                #pragma unroll
                for (int r = 0; r < 4; ++r)
                    Ds[cr + r][col] = (_Float16)(acch[j][r] + bb);
            }
        }
    }
    __syncthreads();

    const int col8 = tid & 15;
    const int d0l = col8 * 8;
    f32x4 cwq[8];
    float cbv[8];
    #pragma unroll
    for (int q = 0; q < 8; ++q) {
        cwq[q] = *(const f32x4*)(cw + (size_t)(n0 + d0l + q) * DCn);
        cbv[q] = cb[n0 + d0l + q];
    }
    const int b  = m0 >> 10;
    const int t0 = m0 & 1023;
    half8 hzero;
    #pragma unroll
    for (int q = 0; q < 8; ++q) hzero[q] = (_Float16)0.f;
    for (int k = 0; k < 8; ++k) {
        const int rr = (tid >> 4) + k * 16;
        half8 w[4];
        #pragma unroll
        for (int jj = 0; jj < 4; ++jj) {
            const int dr = 16 + rr - 3 + jj;
            w[jj] = ((t0 == 0) && (dr < 16)) ? hzero : *(const half8*)&Ds[dr][d0l];
        }
        half8 o;
        #pragma unroll
        for (int q = 0; q < 8; ++q) {
            float a = cbv[q];
            #pragma unroll
            for (int jj = 0; jj < 4; ++jj) a += (float)w[jj][q] * cwq[q][jj];
            o[q] = (_Float16)silu_(a);
        }
        *(half8*)(uh + ((size_t)b * Ln + t0 + rr) * DIn + n0 + d0l) = o;
    }
}

// ---------------- MFMA fp16 GEMM (delta: softplus + bias, proven R7) ----------
__global__ __launch_bounds__(256)
void hgemm_delta(const _Float16* __restrict__ A, const _Float16* __restrict__ Bw,
                 const float* __restrict__ bias, _Float16* __restrict__ Ch) {
    __shared__ _Float16 As[128 * 32];
    __shared__ _Float16 Bs[128 * 32];
    const int tid  = threadIdx.x;
    const int lane = tid & 63, wid = tid >> 6;
    const int wm = wid >> 1, wn = wid & 1;
    const int m0 = blockIdx.y * 128, n0 = blockIdx.x * 128;

    f32x4 acc[4][4] = {};
    for (int k0 = 0; k0 < DTRn; k0 += 32) {
        #pragma unroll
        for (int i = 0; i < 2; ++i) {
            const int off = tid * 16 + i * 4096;
            const int row = off >> 6;
            const int ch  = (off & 63) >> 1;
            __builtin_amdgcn_global_load_lds(
                (const __attribute__((address_space(1))) void*)(A + (size_t)(m0 + row) * XPW + k0 + ch),
                (__attribute__((address_space(3))) void*)(&As[off >> 1]), 16, 0, 0);
            __builtin_amdgcn_global_load_lds(
                (const __attribute__((address_space(1))) void*)(Bw + (size_t)(n0 + row) * DTRn + k0 + ch),
                (__attribute__((address_space(3))) void*)(&Bs[off >> 1]), 16, 0, 0);
        }
        __syncthreads();
        const int ar = lane & 15;
        const int kq = (lane >> 4) * 8;
        half8 af[4], bf[4];
        #pragma unroll
        for (int i = 0; i < 4; ++i)
            af[i] = *(const half8*)&As[(wm * 64 + i * 16 + ar) * 32 + kq];
        #pragma unroll
        for (int j = 0; j < 4; ++j)
            bf[j] = *(const half8*)&Bs[(wn * 64 + j * 16 + ar) * 32 + kq];
        #pragma unroll
        for (int i = 0; i < 4; ++i)
            #pragma unroll
            for (int j = 0; j < 4; ++j)
                acc[i][j] = __builtin_amdgcn_mfma_f32_16x16x32_f16(af[i], bf[j], acc[i][j], 0, 0, 0);
        __syncthreads();
    }
    const int cr = (lane >> 4) * 4;
    const int cn = lane & 15;
    #pragma unroll
    for (int i = 0; i < 4; ++i)
        #pragma unroll
        for (int j = 0; j < 4; ++j) {
            const int n = n0 + wn * 64 + j * 16 + cn;
            #pragma unroll
            for (int r = 0; r < 4; ++r) {
                const int m = m0 + wm * 64 + i * 16 + cr + r;
                Ch[(size_t)m * DIn + n] = (_Float16)softplus_(acc[i][j][r] + bias[n]);
            }
        }
}

// ---------------- chunked scan: 2 adjacent d per thread (half2 loads) ----------------
__global__ __launch_bounds__(256)
void scan_chunk_kernel(const _Float16* __restrict__ delta, const _Float16* __restrict__ u,
                       const _Float16* __restrict__ dtBh, const float* __restrict__ A_log,
                       float* __restrict__ cS, _Float16* __restrict__ cH) {
    const int d0 = blockIdx.x * 512 + threadIdx.x * 2;
    const int c = blockIdx.y, b = blockIdx.z;
    float A0[DSn], A1[DSn], h0[DSn], h1[DSn];
    {
        const float4* al0 = (const float4*)(A_log + (size_t)d0 * DSn);
        const float4* al1 = (const float4*)(A_log + (size_t)(d0 + 1) * DSn);
        #pragma unroll
        for (int q = 0; q < 4; ++q) {
            const float4 v0 = al0[q], v1 = al1[q];
            A0[q * 4 + 0] = -__expf(v0.x); A0[q * 4 + 1] = -__expf(v0.y);
            A0[q * 4 + 2] = -__expf(v0.z); A0[q * 4 + 3] = -__expf(v0.w);
            A1[q * 4 + 0] = -__expf(v1.x); A1[q * 4 + 1] = -__expf(v1.y);
            A1[q * 4 + 2] = -__expf(v1.z); A1[q * 4 + 3] = -__expf(v1.w);
            h0[q * 4 + 0] = 0.f; h0[q * 4 + 1] = 0.f; h0[q * 4 + 2] = 0.f; h0[q * 4 + 3] = 0.f;
            h1[q * 4 + 0] = 0.f; h1[q * 4 + 1] = 0.f; h1[q * 4 + 2] = 0.f; h1[q * 4 + 3] = 0.f;
        }
    }
    const float A00 = A0[0], A10 = A1[0];
    bool structured = true;
    #pragma unroll
    for (int s = 1; s < DSn; ++s) {
        structured = structured && (fabsf(A0[s] - (float)(s + 1) * A00) <= 1e-4f * (s + 1));
        structured = structured && (fabsf(A1[s] - (float)(s + 1) * A10) <= 1e-4f * (s + 1));
    }
    float Ssum0 = 0.f, Ssum1 = 0.f;
    const size_t base = ((size_t)b * Ln + (size_t)c * CHUNK) * DIn + d0;
    const _Float16* Bp = dtBh + ((size_t)b * Ln + (size_t)c * CHUNK) * XPW + DTRn;
    if (structured) {
        #pragma unroll 2
        for (int tt = 0; tt < CHUNK; ++tt) {
            const half2v dl2 = *(const half2v*)(delta + base + (size_t)tt * DIn);
            const half2v uu2 = *(const half2v*)(u + base + (size_t)tt * DIn);
            const float dl0 = (float)dl2[0], dl1 = (float)dl2[1];
            const float du0 = dl0 * (float)uu2[0], du1 = dl1 * (float)uu2[1];
            Ssum0 += dl0; Ssum1 += dl1;
            const half8 bv0 = *(const half8*)(Bp + tt * XPW);
            const half8 bv1 = *(const half8*)(Bp + tt * XPW + 8);
            float Bv[DSn];
            #pragma unroll
            for (int q = 0; q < 8; ++q) { Bv[q] = (float)bv0[q]; Bv[8 + q] = (float)bv1[q]; }
            {
                const float e1 = __expf(dl0 * A00);
                const float e2 = e1 * e1, e4 = e2 * e2, e8 = e4 * e4;
                float E[DSn];
                E[0] = e1;      E[1] = e2;      E[2] = e2 * e1;  E[3] = e4;
                E[4] = e4 * e1; E[5] = e4 * e2; E[6] = E[5] * e1; E[7] = e8;
                E[8] = e8 * e1; E[9] = e8 * e2; E[10] = E[9] * e1; E[11] = e8 * e4;
                E[12] = E[11] * e1; E[13] = E[11] * e2; E[14] = E[13] * e1; E[15] = e8 * e8;
                #pragma unroll
                for (int s = 0; s < DSn; ++s) h0[s] = E[s] * h0[s] + du0 * Bv[s];
            }
            {
                const float e1 = __expf(dl1 * A10);
                const float e2 = e1 * e1, e4 = e2 * e2, e8 = e4 * e4;
                float E[DSn];
                E[0] = e1;      E[1] = e2;      E[2] = e2 * e1;  E[3] = e4;
                E[4] = e4 * e1; E[5] = e4 * e2; E[6] = E[5] * e1; E[7] = e8;
                E[8] = e8 * e1; E[9] = e8 * e2; E[10] = E[9] * e1; E[11] = e8 * e4;
                E[12] = E[11] * e1; E[13] = E[11] * e2; E[14] = E[13] * e1; E[15] = e8 * e8;
                #pragma unroll
                for (int s = 0; s < DSn; ++s) h1[s] = E[s] * h1[s] + du1 * Bv[s];
            }
        }
    } else {
        for (int tt = 0; tt < CHUNK; ++tt) {
            const half2v dl2 = *(const half2v*)(delta + base + (size_t)tt * DIn);
            const half2v uu2 = *(const half2v*)(u + base + (size_t)tt * DIn);
            const float dl0 = (float)dl2[0], dl1 = (float)dl2[1];
            const float du0 = dl0 * (float)uu2[0], du1 = dl1 * (float)uu2[1];
            Ssum0 += dl0; Ssum1 += dl1;
            const half8 bv0 = *(const half8*)(Bp + tt * XPW);
            const half8 bv1 = *(const half8*)(Bp + tt * XPW + 8);
            float Bv[DSn];
            #pragma unroll
            for (int q = 0; q < 8; ++q) { Bv[q] = (float)bv0[q]; Bv[8 + q] = (float)bv1[q]; }
            #pragma unroll
            for (int s = 0; s < DSn; ++s) {
                h0[s] = __expf(dl0 * A0[s]) * h0[s] + du0 * Bv[s];
                h1[s] = __expf(dl1 * A1[s]) * h1[s] + du1 * Bv[s];
            }
        }
    }
    const size_t cidx = ((size_t)b * NCHUNK + c) * DIn + d0;
    *(float2*)(cS + cidx) = float2{Ssum0, Ssum1};
    half8 o0, o1, o2, o3;
    #pragma unroll
    for (int q = 0; q < 8; ++q) {
        o0[q] = (_Float16)h0[q]; o1[q] = (_Float16)h0[8 + q];
        o2[q] = (_Float16)h1[q]; o3[q] = (_Float16)h1[8 + q];
    }
    _Float16* cp = cH + cidx * DSn;
    *(half8*)(cp)      = o0;
    *(half8*)(cp + 8)  = o1;
    *(half8*)(cp + 16) = o2;
    *(half8*)(cp + 24) = o3;
}

// ------- combine: fold chunks + gate + weff dot + atomic out (proven) -------
__global__ __launch_bounds__(256)
void combine_v3(const float* __restrict__ cS, const _Float16* __restrict__ cH,
                const float* __restrict__ A_log, const float* __restrict__ Clast,
                const float* __restrict__ Dp, const _Float16* __restrict__ u,
                const float* __restrict__ zlast, const float* __restrict__ wp,
                float* __restrict__ out) {
    __shared__ float acc[16];
    const int tid = threadIdx.x;
    const int s = tid & 15;
    const int d = blockIdx.x * 16 + (tid >> 4);
    const int b = blockIdx.y;
    const float A = -__expf(A_log[(size_t)d * DSn + s]);
    float h = 0.f;
    const size_t cb0 = (size_t)b * NCHUNK;
    for (int c = 0; c < NCHUNK; ++c) {
        const size_t cidx = (cb0 + c) * DIn + d;
        h = __expf(A * cS[cidx]) * h + (float)cH[cidx * DSn + s];
    }
    float y = h * Clast[b * DSn + s];
    y += __shfl_xor(y, 1);
    y += __shfl_xor(y, 2);
    y += __shfl_xor(y, 4);
    y += __shfl_xor(y, 8);
    if (s == 0) {
        const float ul = (float)u[((size_t)b * Ln + (Ln - 1)) * DIn + d];
        float yy = y + Dp[d] * ul;
        yy *= silu_(zlast[(size_t)b * DIn + d]);
        float w = 0.f;
        #pragma unroll
        for (int c = 0; c < WCH; ++c) w += wp[(size_t)c * DIn + d];
        acc[tid >> 4] = yy * w;
    }
    __syncthreads();
    if (tid == 0) {
        float t = 0.f;
        #pragma unroll
        for (int i = 0; i < 16; ++i) t += acc[i];
        atomicAdd(&out[b], t);
    }
}

} // namespace

extern "C" void kernel_launch(void* const* d_in, const int* in_sizes, int n_in,
                              void* d_out, int out_size, void* d_ws, size_t ws_size,
                              hipStream_t stream) {
    (void)in_sizes; (void)n_in; (void)out_size; (void)ws_size;
    const float* x       = (const float*)d_in[0];
    const float* W_emb   = (const float*)d_in[1];
    const float* b_emb   = (const float*)d_in[2];
    const float* in_proj = (const float*)d_in[3];
    const float* conv_w  = (const float*)d_in[4];
    const float* conv_b  = (const float*)d_in[5];
    const float* x_proj  = (const float*)d_in[6];
    const float* dt_w    = (const float*)d_in[7];
    const float* dt_b    = (const float*)d_in[8];
    const float* A_log   = (const float*)d_in[9];
    const float* Dp      = (const float*)d_in[10];
    const float* out_w   = (const float*)d_in[11];
    const float* fc_w    = (const float*)d_in[12];
    const float* fc_b    = (const float*)d_in[13];
    float* out = (float*)d_out;
    char* w8 = (char*)d_ws;

    const size_t MB = 1ull << 20;
    _Float16* uh       = (_Float16*)(w8 + 16 * MB);  // 16 MB [upre_conv -> dtb/scan/combine]
    float*    wfoldP   = (float*)(w8 + 32 * MB);     // 8 MB [wfold -> skcomb]
    _Float16* deltah   = (_Float16*)(w8 + 32 * MB);  // aliases wfoldP [delta -> scan]
    float*    skp      = (float*)(w8 + 48 * MB);     // 10.5 MB [dtb -> skcombB]
    float*    cS       = skp;                        // aliases skp [scan -> combine], 1 MB
    _Float16* cH       = (_Float16*)(w8 + 50 * MB);  // 8.4 MB [scan -> combine]
    _Float16* dtBh     = (_Float16*)(w8 + 67 * MB);
    _Float16* xh       = (_Float16*)(w8 + 68 * MB);
    _Float16* W_embT_h = (_Float16*)(w8 + 70 * MB);
    _Float16* in_projh = (_Float16*)(w8 + 71 * MB);  // 4 MB (u-half only)
    _Float16* xp_h     = (_Float16*)(w8 + 79 * MB);
    _Float16* dt_wh    = (_Float16*)(w8 + 80 * MB);
    _Float16* Wfoldh   = (_Float16*)(w8 + 81 * MB);  // 1 MB [2048][256]
    float*    wp       = (float*)(w8 + 83 * MB);
    float*    badd     = (float*)(w8 + 84 * MB);     // 8 KB (u-half only used)
    float*    zlast    = badd + 4096;                // 32 KB
    float*    Clast    = zlast + (size_t)Bn * DIn;   // 256 B
    float*    e_last   = Clast + 64;                 // 16 KB [4][1024]

    // 1. prep: conversions (u-half only) + weff + badd-u + out init + e_last
    prep_mega<<<4225, 256, 0, stream>>>(x, xh, in_proj, in_projh, dt_w, dt_wh,
                                        W_emb, W_embT_h, x_proj, xp_h,
                                        fc_w, out_w, wp, b_emb, badd, fc_b, out, e_last);
    // 2. Wfold u-half = in_proj_u @ W_emb (split-K 4, M=2048)
    skgemm2<<<dim3(4, 16, 2), 256, 0, stream>>>(
        in_projh, DMn, W_embT_h, DMn, wfoldP, INn, 256);
    // 3. Wfold partial sum -> fp16
    skcomb<<<2048, 256, 0, stream>>>(wfoldP, Wfoldh, 2048 * INn, 4);
    // 4. fused: upre GEMM (halo) -> LDS -> conv+silu -> uh
    upre_conv<<<dim3(16, 32), 256, 0, stream>>>(xh, Wfoldh, badd, conv_w, conv_b, uh);
    // 5. dtB partials = uh @ xp^T (split-K 8)
    skgemm2<<<dim3(8, 32, 1), 256, 0, stream>>>(uh, DIn, xp_h, DIn, skp, XPW, 256);
    // 6. dtB partial sum (float4) + C_last + zlast (incl. badd-z inline)
    skcombB_clast_zlast<<<848, 256, 0, stream>>>(skp, dtBh, uh, x_proj, Clast,
                                                 in_proj, e_last, b_emb, zlast);
    // 7. delta = fp16(softplus(dtB @ dt_w^T + dt_b))
    hgemm_delta<<<dim3(DIn / 128, ML / 128), 256, 0, stream>>>(dtBh, dt_wh, dt_b, deltah);
    // 8. chunked scan, 2 d per thread (cS aliases skp, dead now)
    scan_chunk_kernel<<<dim3(DIn / 512, NCHUNK, Bn), 256, 0, stream>>>(
        deltah, uh, dtBh, A_log, cS, cH);
    // 9. combine + gate + weff dot + atomic out
    combine_v3<<<dim3(DIn / 16, Bn), 256, 0, stream>>>(
        cS, cH, A_log, Clast, Dp, uh, zlast, wp, out);
}

// Round 18
// 113.135 us; speedup vs baseline: 1.0145x; 1.0145x over previous
//
#include <hip/hip_runtime.h>
#include <cstddef>
#include <cstdint>

namespace {

typedef _Float16 half8 __attribute__((ext_vector_type(8)));
typedef _Float16 half4 __attribute__((ext_vector_type(4)));
typedef float f32x4 __attribute__((ext_vector_type(4)));

constexpr int Bn   = 4;
constexpr int Ln   = 1024;
constexpr int INn  = 256;
constexpr int DMn  = 1024;
constexpr int DSn  = 16;
constexpr int DCn  = 4;
constexpr int DIn  = 2048;
constexpr int DTRn = 64;
constexpr int XPW  = DTRn + DSn;    // 80
constexpr int NCHUNK = 32;
constexpr int CHUNK  = Ln / NCHUNK; // 32
constexpr int WCH  = 32;
constexpr int ML   = Bn * Ln;       // 4096

__device__ __forceinline__ float silu_(float x) { return x / (1.f + __expf(-x)); }
__device__ __forceinline__ float softplus_(float x) {
    return fmaxf(x, 0.f) + __logf(1.f + __expf(-fabsf(x)));
}

// ================= prep (block-range dispatch) =================
__global__ __launch_bounds__(256)
void prep_mega(const float* __restrict__ x, _Float16* __restrict__ xh,
               const float* __restrict__ ip, _Float16* __restrict__ iph,
               const float* __restrict__ dtw, _Float16* __restrict__ dtwh,
               const float* __restrict__ W_emb, _Float16* __restrict__ W_embT,
               const float* __restrict__ x_proj, _Float16* __restrict__ xp_h,
               const float* __restrict__ fc_w, const float* __restrict__ out_w,
               float* __restrict__ wp,
               const float* __restrict__ b_emb, float* __restrict__ badd,
               const float* __restrict__ fc_b, float* __restrict__ out,
               float* __restrict__ e_last) {
    __shared__ float tile[32][33];
    const int bid = blockIdx.x, tid = threadIdx.x;
    if (bid < 4096) {
        const int n = bid;
        const float4 v = ((const float4*)ip)[n * 256 + tid];
        if (n < 2048)
            ((half4*)iph)[n * 256 + tid] =
                half4{(_Float16)v.x, (_Float16)v.y, (_Float16)v.z, (_Float16)v.w};
        const float4 bv = ((const float4*)b_emb)[tid];
        float s = v.x * bv.x + v.y * bv.y + v.z * bv.z + v.w * bv.w;
        for (int off = 32; off > 0; off >>= 1) s += __shfl_down(s, off);
        if ((tid & 63) == 0) tile[0][tid >> 6] = s;
        __syncthreads();
        if (tid == 0) badd[n] = tile[0][0] + tile[0][1] + tile[0][2] + tile[0][3];
    } else if (bid < 5248) {
        const float* in; _Float16* outp; int i;
        if (bid < 5120) { in = x;   outp = xh;   i = (bid - 4096) * 256 + tid; }
        else            { in = dtw; outp = dtwh; i = (bid - 5120) * 256 + tid; }
        const float4 v = ((const float4*)in)[i];
        ((half4*)outp)[i] = half4{(_Float16)v.x, (_Float16)v.y, (_Float16)v.z, (_Float16)v.w};
    } else if (bid < 5504) {
        const int bx = bid - 5248;
        const int m0 = (bx & 31) * 32, c0 = (bx >> 5) * 32;
        const int lc = tid & 31, lr = tid >> 5;
        #pragma unroll
        for (int ph = 0; ph < 4; ++ph)
            tile[lr + ph * 8][lc] = W_emb[(size_t)(m0 + lr + ph * 8) * INn + c0 + lc];
        __syncthreads();
        #pragma unroll
        for (int ph = 0; ph < 4; ++ph)
            W_embT[(size_t)(c0 + lr + ph * 8) * DMn + m0 + lc] = (_Float16)tile[lc][lr + ph * 8];
    } else if (bid < 5760) {
        const int i = (bid - 5504) * 256 + tid;
        const int r = i >> 9;
        const int c4 = i & 511;
        half4 h;
        if (r < XPW) {
            const float4 v = ((const float4*)(x_proj + (size_t)r * DIn))[c4];
            h = half4{(_Float16)v.x, (_Float16)v.y, (_Float16)v.z, (_Float16)v.w};
        } else {
            h = half4{(_Float16)0.f, (_Float16)0.f, (_Float16)0.f, (_Float16)0.f};
        }
        ((half4*)(xp_h + (size_t)r * DIn))[c4] = h;
    } else if (bid < 6016) {
        const int bx = bid - 5760;
        const int d = (bx & 7) * 256 + tid;
        const int c = bx >> 3;
        const int mstep = DMn / WCH;
        float s = 0.f;
        for (int m = c * mstep; m < (c + 1) * mstep; ++m)
            s += fc_w[m] * out_w[(size_t)m * DIn + d];
        wp[(size_t)c * DIn + d] = s;
    } else if (bid == 6016) {
        if (tid < Bn) out[tid] = fc_b[0];
    } else {
        const int m = (bid - 6017) * 4 + (tid >> 6);   // 0..1023
        const int lane = tid & 63;
        const float4 wq = ((const float4*)(W_emb + (size_t)m * INn))[lane];
        float s0, s1, s2, s3;
        {
            const float4 v = ((const float4*)(x + ((size_t)0 * Ln + (Ln - 1)) * INn))[lane];
            s0 = wq.x * v.x + wq.y * v.y + wq.z * v.z + wq.w * v.w;
        }
        {
            const float4 v = ((const float4*)(x + ((size_t)1 * Ln + (Ln - 1)) * INn))[lane];
            s1 = wq.x * v.x + wq.y * v.y + wq.z * v.z + wq.w * v.w;
        }
        {
            const float4 v = ((const float4*)(x + ((size_t)2 * Ln + (Ln - 1)) * INn))[lane];
            s2 = wq.x * v.x + wq.y * v.y + wq.z * v.z + wq.w * v.w;
        }
        {
            const float4 v = ((const float4*)(x + ((size_t)3 * Ln + (Ln - 1)) * INn))[lane];
            s3 = wq.x * v.x + wq.y * v.y + wq.z * v.z + wq.w * v.w;
        }
        for (int off = 32; off > 0; off >>= 1) {
            s0 += __shfl_down(s0, off);
            s1 += __shfl_down(s1, off);
            s2 += __shfl_down(s2, off);
            s3 += __shfl_down(s3, off);
        }
        if (lane == 0) {
            e_last[0 * DMn + m] = s0;
            e_last[1 * DMn + m] = s1;
            e_last[2 * DMn + m] = s2;
            e_last[3 * DMn + m] = s3;
        }
    }
}

// ---------------- generic split-K MFMA GEMM -> fp32 partials (proven) ----------------
__global__ __launch_bounds__(256)
void skgemm2(const _Float16* __restrict__ A, int lda,
             const _Float16* __restrict__ Bw, int ldb,
             float* __restrict__ P, int N, int Kc) {
    __shared__ _Float16 As[128 * 32];
    __shared__ _Float16 Bs[128 * 32];
    const int tid  = threadIdx.x;
    const int lane = tid & 63, wid = tid >> 6;
    const int wm = wid >> 1, wn = wid & 1;
    const int sk = blockIdx.x;
    const int m0 = blockIdx.y * 128;
    const int n0 = blockIdx.z * 128;
    const int M  = gridDim.y * 128;

    f32x4 acc[4][4] = {};
    const int kbeg = sk * Kc;
    for (int k0 = kbeg; k0 < kbeg + Kc; k0 += 32) {
        #pragma unroll
        for (int i = 0; i < 2; ++i) {
            const int off = tid * 16 + i * 4096;
            const int row = off >> 6;
            const int ch  = (off & 63) >> 1;
            __builtin_amdgcn_global_load_lds(
                (const __attribute__((address_space(1))) void*)(A + (size_t)(m0 + row) * lda + k0 + ch),
                (__attribute__((address_space(3))) void*)(&As[off >> 1]), 16, 0, 0);
            __builtin_amdgcn_global_load_lds(
                (const __attribute__((address_space(1))) void*)(Bw + (size_t)(n0 + row) * ldb + k0 + ch),
                (__attribute__((address_space(3))) void*)(&Bs[off >> 1]), 16, 0, 0);
        }
        __syncthreads();
        const int ar = lane & 15;
        const int kq = (lane >> 4) * 8;
        half8 af[4], bf[4];
        #pragma unroll
        for (int i = 0; i < 4; ++i)
            af[i] = *(const half8*)&As[(wm * 64 + i * 16 + ar) * 32 + kq];
        #pragma unroll
        for (int j = 0; j < 4; ++j)
            bf[j] = *(const half8*)&Bs[(wn * 64 + j * 16 + ar) * 32 + kq];
        #pragma unroll
        for (int i = 0; i < 4; ++i)
            #pragma unroll
            for (int j = 0; j < 4; ++j)
                acc[i][j] = __builtin_amdgcn_mfma_f32_16x16x32_f16(af[i], bf[j], acc[i][j], 0, 0, 0);
        __syncthreads();
    }
    const int cr = (lane >> 4) * 4;
    const int cn = lane & 15;
    #pragma unroll
    for (int i = 0; i < 4; ++i)
        #pragma unroll
        for (int j = 0; j < 4; ++j) {
            const int n = n0 + wn * 64 + j * 16 + cn;
            if (n < N) {
                #pragma unroll
                for (int r = 0; r < 4; ++r) {
                    const int m = m0 + wm * 64 + i * 16 + cr + r;
                    P[((size_t)sk * M + m) * N + n] = acc[i][j][r];
                }
            }
        }
}

// sum split-K partials -> fp16 (Wfold u-half)
__global__ __launch_bounds__(256)
void skcomb(const float* __restrict__ P, _Float16* __restrict__ out, int total, int nsk) {
    const int i = blockIdx.x * 256 + threadIdx.x;
    if (i >= total) return;
    float s = 0.f;
    for (int k = 0; k < nsk; ++k) s += P[(size_t)k * total + i];
    out[i] = (_Float16)s;
}

// node 6: dtB sum ([0,1280)) + clast ([1280,1296)) + zlast fp32 wave-per-j ([1296,1808))
__global__ __launch_bounds__(256)
void skcombB_clast_zlast(const float* __restrict__ P, _Float16* __restrict__ dtBh,
                         const _Float16* __restrict__ u, const float* __restrict__ x_proj,
                         float* __restrict__ Clast,
                         const float* __restrict__ ip, const float* __restrict__ e_last,
                         const float* __restrict__ badd, float* __restrict__ zlast) {
    const int bid = blockIdx.x, tid = threadIdx.x;
    if (bid < 1280) {
        const int i = bid * 256 + tid;
        float s = 0.f;
        #pragma unroll
        for (int k = 0; k < 8; ++k) s += P[(size_t)k * (ML * XPW) + i];
        dtBh[i] = (_Float16)s;
    } else if (bid < 1296) {
        const int wave = tid >> 6, lane = tid & 63;
        const int task = (bid - 1280) * 4 + wave;
        const int s_idx = task & 15, b = task >> 4;
        const _Float16* ur = u + ((size_t)b * Ln + (Ln - 1)) * DIn;
        const float* w = x_proj + (size_t)(XPW + s_idx) * DIn;
        float s = 0.f;
        for (int k = lane; k < DIn; k += 64) s += (float)ur[k] * w[k];
        for (int off = 32; off > 0; off >>= 1) s += __shfl_down(s, off);
        if (lane == 0) Clast[b * DSn + s_idx] = s;
    } else {
        // zlast[b][j] = e_last[b] . in_proj[DIn+j] (fp32) + badd[DIn+j]; wave per j, 4 b's
        const int wave = tid >> 6, lane = tid & 63;
        const int j = (bid - 1296) * 4 + wave;    // 0..2047
        const float4* row = (const float4*)(ip + (size_t)(DIn + j) * DMn);
        const float4 w0 = row[lane * 4 + 0];
        const float4 w1 = row[lane * 4 + 1];
        const float4 w2 = row[lane * 4 + 2];
        const float4 w3 = row[lane * 4 + 3];
        const float* el = e_last + lane * 16;
        float s0 = 0.f, s1 = 0.f, s2 = 0.f, s3 = 0.f;
        #pragma unroll
        for (int b = 0; b < 4; ++b) {
            const float4 e0 = ((const float4*)(el + b * DMn))[0];
            const float4 e1 = ((const float4*)(el + b * DMn))[1];
            const float4 e2 = ((const float4*)(el + b * DMn))[2];
            const float4 e3 = ((const float4*)(el + b * DMn))[3];
            const float v = w0.x * e0.x + w0.y * e0.y + w0.z * e0.z + w0.w * e0.w
                          + w1.x * e1.x + w1.y * e1.y + w1.z * e1.z + w1.w * e1.w
                          + w2.x * e2.x + w2.y * e2.y + w2.z * e2.z + w2.w * e2.w
                          + w3.x * e3.x + w3.y * e3.y + w3.z * e3.z + w3.w * e3.w;
            if (b == 0) s0 = v; else if (b == 1) s1 = v; else if (b == 2) s2 = v; else s3 = v;
        }
        for (int off = 32; off > 0; off >>= 1) {
            s0 += __shfl_down(s0, off);
            s1 += __shfl_down(s1, off);
            s2 += __shfl_down(s2, off);
            s3 += __shfl_down(s3, off);
        }
        if (lane == 0) {
            const float ba = badd[DIn + j];
            zlast[0 * DIn + j] = s0 + ba;
            zlast[1 * DIn + j] = s1 + ba;
            zlast[2 * DIn + j] = s2 + ba;
            zlast[3 * DIn + j] = s3 + ba;
        }
    }
}

// ======== upre_conv: upre GEMM (+16-row halo) -> LDS -> conv+silu -> uh (proven R13) ========
__global__ __launch_bounds__(256)
void upre_conv(const _Float16* __restrict__ xh, const _Float16* __restrict__ Wfoldh,
               const float* __restrict__ badd,
               const float* __restrict__ cw, const float* __restrict__ cb,
               _Float16* __restrict__ uh) {
    __shared__ _Float16 smem[144 * 132];
    _Float16* As = smem;
    _Float16* Bs = smem + 144 * 32;
    _Float16 (*Ds)[132] = (_Float16 (*)[132])smem;

    const int tid = threadIdx.x;
    const int lane = tid & 63, wid = tid >> 6;
    const int wm = wid >> 1, wn = wid & 1;
    const int m0 = blockIdx.y * 128, n0 = blockIdx.x * 128;

    f32x4 acc[4][4] = {};
    f32x4 acch[4] = {};
    for (int k0 = 0; k0 < INn; k0 += 32) {
        #pragma unroll
        for (int i = 0; i < 2; ++i) {
            const int off = tid * 16 + i * 4096;
            const int row = off >> 6;
            const int ch  = (off & 63) >> 1;
            int srow = m0 - 16 + row;
            if (srow < 0) srow = 0;
            __builtin_amdgcn_global_load_lds(
                (const __attribute__((address_space(1))) void*)(xh + (size_t)srow * INn + k0 + ch),
                (__attribute__((address_space(3))) void*)(&As[off >> 1]), 16, 0, 0);
            const _Float16* gb = Wfoldh + (size_t)(n0 + row) * INn + k0 + ch;
            __builtin_amdgcn_global_load_lds(
                (const __attribute__((address_space(1))) void*)gb,
                (__attribute__((address_space(3))) void*)(&Bs[off >> 1]), 16, 0, 0);
        }
        if (tid < 64) {
            const int off = tid * 16 + 8192;
            const int row = off >> 6;
            const int ch  = (off & 63) >> 1;
            __builtin_amdgcn_global_load_lds(
                (const __attribute__((address_space(1))) void*)(xh + (size_t)(m0 - 16 + row) * INn + k0 + ch),
                (__attribute__((address_space(3))) void*)(&As[off >> 1]), 16, 0, 0);
        }
        __syncthreads();
        const int ar = lane & 15;
        const int kq = (lane >> 4) * 8;
        half8 af[4], bf[4];
        #pragma unroll
        for (int i = 0; i < 4; ++i)
            af[i] = *(const half8*)&As[(16 + wm * 64 + i * 16 + ar) * 32 + kq];
        #pragma unroll
        for (int j = 0; j < 4; ++j)
            bf[j] = *(const half8*)&Bs[(wn * 64 + j * 16 + ar) * 32 + kq];
        #pragma unroll
        for (int i = 0; i < 4; ++i)
            #pragma unroll
            for (int j = 0; j < 4; ++j)
                acc[i][j] = __builtin_amdgcn_mfma_f32_16x16x32_f16(af[i], bf[j], acc[i][j], 0, 0, 0);
        if (wm == 0) {
            const half8 afh = *(const half8*)&As[ar * 32 + kq];
            #pragma unroll
            for (int j = 0; j < 4; ++j)
                acch[j] = __builtin_amdgcn_mfma_f32_16x16x32_f16(afh, bf[j], acch[j], 0, 0, 0);
        }
        __syncthreads();
    }

    {
        const int cr = (lane >> 4) * 4;
        const int cn = lane & 15;
        #pragma unroll
        for (int i = 0; i < 4; ++i)
            #pragma unroll
            for (int j = 0; j < 4; ++j) {
                const int col = wn * 64 + j * 16 + cn;
                const float bb = badd[n0 + col];
                #pragma unroll
                for (int r = 0; r < 4; ++r)
                    Ds[16 + wm * 64 + i * 16 + cr + r][col] = (_Float16)(acc[i][j][r] + bb);
            }
        if (wm == 0) {
            #pragma unroll
            for (int j = 0; j < 4; ++j) {
                const int col = wn * 64 + j * 16 + cn;
                const float bb = badd[n0 + col];
                #pragma unroll
                for (int r = 0; r < 4; ++r)
                    Ds[cr + r][col] = (_Float16)(acch[j][r] + bb);
            }
        }
    }
    __syncthreads();

    const int col8 = tid & 15;
    const int d0l = col8 * 8;
    f32x4 cwq[8];
    float cbv[8];
    #pragma unroll
    for (int q = 0; q < 8; ++q) {
        cwq[q] = *(const f32x4*)(cw + (size_t)(n0 + d0l + q) * DCn);
        cbv[q] = cb[n0 + d0l + q];
    }
    const int b  = m0 >> 10;
    const int t0 = m0 & 1023;
    half8 hzero;
    #pragma unroll
    for (int q = 0; q < 8; ++q) hzero[q] = (_Float16)0.f;
    for (int k = 0; k < 8; ++k) {
        const int rr = (tid >> 4) + k * 16;
        half8 w[4];
        #pragma unroll
        for (int jj = 0; jj < 4; ++jj) {
            const int dr = 16 + rr - 3 + jj;
            w[jj] = ((t0 == 0) && (dr < 16)) ? hzero : *(const half8*)&Ds[dr][d0l];
        }
        half8 o;
        #pragma unroll
        for (int q = 0; q < 8; ++q) {
            float a = cbv[q];
            #pragma unroll
            for (int jj = 0; jj < 4; ++jj) a += (float)w[jj][q] * cwq[q][jj];
            o[q] = (_Float16)silu_(a);
        }
        *(half8*)(uh + ((size_t)b * Ln + t0 + rr) * DIn + n0 + d0l) = o;
    }
}

// ---------------- MFMA fp16 GEMM (delta: softplus + bias, proven R7) ----------
__global__ __launch_bounds__(256)
void hgemm_delta(const _Float16* __restrict__ A, const _Float16* __restrict__ Bw,
                 const float* __restrict__ bias, _Float16* __restrict__ Ch) {
    __shared__ _Float16 As[128 * 32];
    __shared__ _Float16 Bs[128 * 32];
    const int tid  = threadIdx.x;
    const int lane = tid & 63, wid = tid >> 6;
    const int wm = wid >> 1, wn = wid & 1;
    const int m0 = blockIdx.y * 128, n0 = blockIdx.x * 128;

    f32x4 acc[4][4] = {};
    for (int k0 = 0; k0 < DTRn; k0 += 32) {
        #pragma unroll
        for (int i = 0; i < 2; ++i) {
            const int off = tid * 16 + i * 4096;
            const int row = off >> 6;
            const int ch  = (off & 63) >> 1;
            __builtin_amdgcn_global_load_lds(
                (const __attribute__((address_space(1))) void*)(A + (size_t)(m0 + row) * XPW + k0 + ch),
                (__attribute__((address_space(3))) void*)(&As[off >> 1]), 16, 0, 0);
            __builtin_amdgcn_global_load_lds(
                (const __attribute__((address_space(1))) void*)(Bw + (size_t)(n0 + row) * DTRn + k0 + ch),
                (__attribute__((address_space(3))) void*)(&Bs[off >> 1]), 16, 0, 0);
        }
        __syncthreads();
        const int ar = lane & 15;
        const int kq = (lane >> 4) * 8;
        half8 af[4], bf[4];
        #pragma unroll
        for (int i = 0; i < 4; ++i)
            af[i] = *(const half8*)&As[(wm * 64 + i * 16 + ar) * 32 + kq];
        #pragma unroll
        for (int j = 0; j < 4; ++j)
            bf[j] = *(const half8*)&Bs[(wn * 64 + j * 16 + ar) * 32 + kq];
        #pragma unroll
        for (int i = 0; i < 4; ++i)
            #pragma unroll
            for (int j = 0; j < 4; ++j)
                acc[i][j] = __builtin_amdgcn_mfma_f32_16x16x32_f16(af[i], bf[j], acc[i][j], 0, 0, 0);
        __syncthreads();
    }
    const int cr = (lane >> 4) * 4;
    const int cn = lane & 15;
    #pragma unroll
    for (int i = 0; i < 4; ++i)
        #pragma unroll
        for (int j = 0; j < 4; ++j) {
            const int n = n0 + wn * 64 + j * 16 + cn;
            #pragma unroll
            for (int r = 0; r < 4; ++r) {
                const int m = m0 + wm * 64 + i * 16 + cr + r;
                Ch[(size_t)m * DIn + n] = (_Float16)softplus_(acc[i][j][r] + bias[n]);
            }
        }
}

// ---------------- chunked scan (powers-trick, NCHUNK=32) ----------------
__global__ __launch_bounds__(256)
void scan_chunk_kernel(const _Float16* __restrict__ delta, const _Float16* __restrict__ u,
                       const _Float16* __restrict__ dtBh, const float* __restrict__ A_log,
                       float* __restrict__ cS, _Float16* __restrict__ cH) {
    const int d = blockIdx.x * 256 + threadIdx.x;
    const int c = blockIdx.y, b = blockIdx.z;
    float A[DSn], h[DSn];
    const float4* al = (const float4*)(A_log + (size_t)d * DSn);
    #pragma unroll
    for (int q = 0; q < 4; ++q) {
        const float4 v = al[q];
        A[q * 4 + 0] = -__expf(v.x); A[q * 4 + 1] = -__expf(v.y);
        A[q * 4 + 2] = -__expf(v.z); A[q * 4 + 3] = -__expf(v.w);
        h[q * 4 + 0] = 0.f; h[q * 4 + 1] = 0.f; h[q * 4 + 2] = 0.f; h[q * 4 + 3] = 0.f;
    }
    const float A0 = A[0];
    bool structured = true;
    #pragma unroll
    for (int s = 1; s < DSn; ++s)
        structured = structured && (fabsf(A[s] - (float)(s + 1) * A0) <= 1e-4f * (s + 1));
    float Ssum = 0.f;
    const size_t base = ((size_t)b * Ln + (size_t)c * CHUNK) * DIn + d;
    const _Float16* Bp = dtBh + ((size_t)b * Ln + (size_t)c * CHUNK) * XPW + DTRn;
    if (structured) {
        #pragma unroll 4
        for (int tt = 0; tt < CHUNK; ++tt) {
            const float dl = (float)delta[base + (size_t)tt * DIn];
            const float uu = (float)u[base + (size_t)tt * DIn];
            const float du = dl * uu;
            Ssum += dl;
            const half8 bv0 = *(const half8*)(Bp + tt * XPW);
            const half8 bv1 = *(const half8*)(Bp + tt * XPW + 8);
            float Bv[DSn];
            #pragma unroll
            for (int q = 0; q < 8; ++q) { Bv[q] = (float)bv0[q]; Bv[8 + q] = (float)bv1[q]; }
            const float e1 = __expf(dl * A0);
            const float e2 = e1 * e1, e4 = e2 * e2, e8 = e4 * e4;
            float E[DSn];
            E[0] = e1;      E[1] = e2;      E[2] = e2 * e1;  E[3] = e4;
            E[4] = e4 * e1; E[5] = e4 * e2; E[6] = E[5] * e1; E[7] = e8;
            E[8] = e8 * e1; E[9] = e8 * e2; E[10] = E[9] * e1; E[11] = e8 * e4;
            E[12] = E[11] * e1; E[13] = E[11] * e2; E[14] = E[13] * e1; E[15] = e8 * e8;
            #pragma unroll
            for (int s = 0; s < DSn; ++s) h[s] = E[s] * h[s] + du * Bv[s];
        }
    } else {
        #pragma unroll 4
        for (int tt = 0; tt < CHUNK; ++tt) {
            const float dl = (float)delta[base + (size_t)tt * DIn];
            const float uu = (float)u[base + (size_t)tt * DIn];
            const float du = dl * uu;
            Ssum += dl;
            const half8 bv0 = *(const half8*)(Bp + tt * XPW);
            const half8 bv1 = *(const half8*)(Bp + tt * XPW + 8);
            float Bv[DSn];
            #pragma unroll
            for (int q = 0; q < 8; ++q) { Bv[q] = (float)bv0[q]; Bv[8 + q] = (float)bv1[q]; }
            #pragma unroll
            for (int s = 0; s < DSn; ++s) h[s] = __expf(dl * A[s]) * h[s] + du * Bv[s];
        }
    }
    const size_t cidx = ((size_t)b * NCHUNK + c) * DIn + d;
    cS[cidx] = Ssum;
    half8 o0, o1;
    #pragma unroll
    for (int q = 0; q < 8; ++q) { o0[q] = (_Float16)h[q]; o1[q] = (_Float16)h[8 + q]; }
    *(half8*)(cH + cidx * DSn) = o0;
    *(half8*)(cH + cidx * DSn + 8) = o1;
}

// ------- combine: fold chunks + gate + weff dot + atomic out (proven) -------
__global__ __launch_bounds__(256)
void combine_v3(const float* __restrict__ cS, const _Float16* __restrict__ cH,
                const float* __restrict__ A_log, const float* __restrict__ Clast,
                const float* __restrict__ Dp, const _Float16* __restrict__ u,
                const float* __restrict__ zlast, const float* __restrict__ wp,
                float* __restrict__ out) {
    __shared__ float acc[16];
    const int tid = threadIdx.x;
    const int s = tid & 15;
    const int d = blockIdx.x * 16 + (tid >> 4);
    const int b = blockIdx.y;
    const float A = -__expf(A_log[(size_t)d * DSn + s]);
    float h = 0.f;
    const size_t cb0 = (size_t)b * NCHUNK;
    for (int c = 0; c < NCHUNK; ++c) {
        const size_t cidx = (cb0 + c) * DIn + d;
        h = __expf(A * cS[cidx]) * h + (float)cH[cidx * DSn + s];
    }
    float y = h * Clast[b * DSn + s];
    y += __shfl_xor(y, 1);
    y += __shfl_xor(y, 2);
    y += __shfl_xor(y, 4);
    y += __shfl_xor(y, 8);
    if (s == 0) {
        const float ul = (float)u[((size_t)b * Ln + (Ln - 1)) * DIn + d];
        float yy = y + Dp[d] * ul;
        yy *= silu_(zlast[(size_t)b * DIn + d]);
        float w = 0.f;
        #pragma unroll
        for (int c = 0; c < WCH; ++c) w += wp[(size_t)c * DIn + d];
        acc[tid >> 4] = yy * w;
    }
    __syncthreads();
    if (tid == 0) {
        float t = 0.f;
        #pragma unroll
        for (int i = 0; i < 16; ++i) t += acc[i];
        atomicAdd(&out[b], t);
    }
}

} // namespace

extern "C" void kernel_launch(void* const* d_in, const int* in_sizes, int n_in,
                              void* d_out, int out_size, void* d_ws, size_t ws_size,
                              hipStream_t stream) {
    (void)in_sizes; (void)n_in; (void)out_size; (void)ws_size;
    const float* x       = (const float*)d_in[0];
    const float* W_emb   = (const float*)d_in[1];
    const float* b_emb   = (const float*)d_in[2];
    const float* in_proj = (const float*)d_in[3];
    const float* conv_w  = (const float*)d_in[4];
    const float* conv_b  = (const float*)d_in[5];
    const float* x_proj  = (const float*)d_in[6];
    const float* dt_w    = (const float*)d_in[7];
    const float* dt_b    = (const float*)d_in[8];
    const float* A_log   = (const float*)d_in[9];
    const float* Dp      = (const float*)d_in[10];
    const float* out_w   = (const float*)d_in[11];
    const float* fc_w    = (const float*)d_in[12];
    const float* fc_b    = (const float*)d_in[13];
    float* out = (float*)d_out;
    char* w8 = (char*)d_ws;

    const size_t MB = 1ull << 20;
    _Float16* uh       = (_Float16*)(w8 + 16 * MB);  // 16 MB [upre_conv -> dtb/scan/combine]
    float*    wfoldP   = (float*)(w8 + 32 * MB);     // 8 MB [wfold -> skcomb]
    _Float16* deltah   = (_Float16*)(w8 + 32 * MB);  // aliases wfoldP [delta -> scan]
    float*    skp      = (float*)(w8 + 48 * MB);     // 10.5 MB [dtb -> skcombB]
    float*    cS       = skp;                        // aliases skp [scan -> combine], 1 MB
    _Float16* cH       = (_Float16*)(w8 + 50 * MB);  // 8.4 MB [scan -> combine]
    _Float16* dtBh     = (_Float16*)(w8 + 67 * MB);
    _Float16* xh       = (_Float16*)(w8 + 68 * MB);
    _Float16* W_embT_h = (_Float16*)(w8 + 70 * MB);
    _Float16* in_projh = (_Float16*)(w8 + 71 * MB);  // 4 MB (u-half only)
    _Float16* xp_h     = (_Float16*)(w8 + 79 * MB);
    _Float16* dt_wh    = (_Float16*)(w8 + 80 * MB);
    _Float16* Wfoldh   = (_Float16*)(w8 + 81 * MB);  // 1 MB [2048][256]
    float*    wp       = (float*)(w8 + 83 * MB);
    float*    badd     = (float*)(w8 + 84 * MB);     // 16 KB
    float*    zlast    = badd + 4096;                // 32 KB
    float*    Clast    = zlast + (size_t)Bn * DIn;   // 256 B
    float*    e_last   = Clast + 64;                 // 16 KB [4][1024]

    // 1. prep: conversions (u-half only) + weff + badd + out init + e_last
    prep_mega<<<6273, 256, 0, stream>>>(x, xh, in_proj, in_projh, dt_w, dt_wh,
                                        W_emb, W_embT_h, x_proj, xp_h,
                                        fc_w, out_w, wp, b_emb, badd, fc_b, out, e_last);
    // 2. Wfold u-half = in_proj_u @ W_emb (split-K 4, M=2048)
    skgemm2<<<dim3(4, 16, 2), 256, 0, stream>>>(
        in_projh, DMn, W_embT_h, DMn, wfoldP, INn, 256);
    // 3. Wfold partial sum -> fp16
    skcomb<<<2048, 256, 0, stream>>>(wfoldP, Wfoldh, 2048 * INn, 4);
    // 4. fused: upre GEMM (halo) -> LDS -> conv+silu -> uh
    upre_conv<<<dim3(16, 32), 256, 0, stream>>>(xh, Wfoldh, badd, conv_w, conv_b, uh);
    // 5. dtB partials = uh @ xp^T (split-K 8)
    skgemm2<<<dim3(8, 32, 1), 256, 0, stream>>>(uh, DIn, xp_h, DIn, skp, XPW, 256);
    // 6. dtB partial sum + C_last + zlast (fp32, wave-per-j)
    skcombB_clast_zlast<<<1808, 256, 0, stream>>>(skp, dtBh, uh, x_proj, Clast,
                                                  in_proj, e_last, badd, zlast);
    // 7. delta = fp16(softplus(dtB @ dt_w^T + dt_b))
    hgemm_delta<<<dim3(DIn / 128, ML / 128), 256, 0, stream>>>(dtBh, dt_wh, dt_b, deltah);
    // 8. chunked scan, 32 chunks of 32 steps (cS aliases skp, dead now)
    scan_chunk_kernel<<<dim3(DIn / 256, NCHUNK, Bn), 256, 0, stream>>>(
        deltah, uh, dtBh, A_log, cS, cH);
    // 9. combine + gate + weff dot + atomic out
    combine_v3<<<dim3(DIn / 16, Bn), 256, 0, stream>>>(
        cS, cH, A_log, Clast, Dp, uh, zlast, wp, out);
}